// Round 14
// baseline (127.990 us; speedup 1.0000x reference)
//
#include <hip/hip_runtime.h>
#include <hip/hip_bf16.h>
#include <math.h>

#define N 1024
#define D 64
#define ALPHA 0.2f
#define LN_EPS 1e-5f
#define MASK_VAL -1000000000.0f

typedef __attribute__((ext_vector_type(8))) short bf16x8;
typedef __attribute__((ext_vector_type(4))) float f32x4;

__device__ __forceinline__ float leaky(float x) { return fmaxf(x, ALPHA * x); }

__device__ __forceinline__ unsigned f2bf_u(float f) {
    unsigned u = __builtin_bit_cast(unsigned, f);
    u += 0x7fffu + ((u >> 16) & 1u);
    return u >> 16;
}
__device__ __forceinline__ short f2bf(float f) { return (short)f2bf_u(f); }

// |x|,|y| -> packed bf16 dword via hw v_cvt_pk_bf16_f32 (abs folds into
// VOP3 src modifiers).
__device__ __forceinline__ unsigned abs_cvt_pair(float x, float y) {
    __hip_bfloat162 b = __float22bfloat162_rn(make_float2(fabsf(x), fabsf(y)));
    unsigned u;
    __builtin_memcpy(&u, &b, 4);
    return u;
}

__device__ __forceinline__ f32x4 leaky4(f32x4 v) {
    return __builtin_elementwise_max(v, v * ALPHA);
}

union BF8 { bf16x8 v; unsigned u[4]; };

// ---------------------------------------------------------------------------
// Kernel 1: projections + leaky factoring folds. 4 rows per block.
//   leaky(X) = 0.6X + 0.4|X|, X = ei + ejB (ejB includes edge_b) =>
//   ajF = Wh@A_j + 0.6*(ejB@Ae)       (row-major [j][o])
//   aiF = Wh@A_i + b1 + 0.6*(ei@Ae)
// ---------------------------------------------------------------------------
__global__ __launch_bounds__(256) void gat_precompute(
    const float* __restrict__ h, const float* __restrict__ W,
    const float* __restrict__ attn_w1, const float* __restrict__ attn_b1,
    const float* __restrict__ edge_w, const float* __restrict__ edge_b,
    float* __restrict__ Wh, float* __restrict__ ejB, float* __restrict__ ei_o,
    float* __restrict__ ajF, float* __restrict__ aiF)
{
    const int tid = threadIdx.x;
    const int r = tid >> 6;
    const int k = tid & 63;
    const int i = blockIdx.x * 4 + r;
    const float* __restrict__ Ae = attn_w1 + 2 * D * D;
    __shared__ float hrow[4][D], whrow[4][D], eirow[4][D], ejrow[4][D];

    hrow[r][k] = h[(size_t)i * D + k];
    __syncthreads();

    float wh = 0.f, vei = 0.f, vej = 0.f;
    #pragma unroll 8
    for (int m = 0; m < D; ++m) {
        float hm = hrow[r][m];
        wh  = fmaf(hm, W[m * D + k], wh);
        vei = fmaf(hm, edge_w[m * D + k], vei);
        vej = fmaf(hm, edge_w[(m + D) * D + k], vej);
    }
    vej += edge_b[k];
    Wh[(size_t)i * D + k]   = wh;
    ei_o[(size_t)i * D + k] = vei;
    ejB[(size_t)i * D + k]  = vej;
    whrow[r][k] = wh; eirow[r][k] = vei; ejrow[r][k] = vej;
    __syncthreads();

    float vai = 0.f, vaj = 0.f, vea = 0.f, veb = 0.f;
    #pragma unroll 8
    for (int m = 0; m < D; ++m) {
        float wm = whrow[r][m];
        float aem = Ae[m * D + k];
        vai = fmaf(wm, attn_w1[m * D + k], vai);
        vaj = fmaf(wm, attn_w1[(m + D) * D + k], vaj);
        vea = fmaf(ejrow[r][m], aem, vea);
        veb = fmaf(eirow[r][m], aem, veb);
    }
    ajF[(size_t)i * D + k] = vaj + 0.6f * vea;
    aiF[(size_t)i * D + k] = vai + attn_b1[k] + 0.6f * veb;
}

// ---------------------------------------------------------------------------
// Kernel 2: scores. Block = 4 i's x 64 j's; grid 4096 x 4 waves.
// R14: IG 8->4 — 4096 blocks vs 2048. With ~7-8 resident blocks/CU this
// gives ~2 pipelined generations per CU (R13's 2048 = exactly one
// generation: simultaneous staging rush + lockstep drain, nothing to
// overlap). 0.4*Ae staged via LDS transposed bf16 (AeT[o][k], stride 72).
// ---------------------------------------------------------------------------
#define IG 4
#define AEK 72   // AeT row stride in shorts (16B-aligned rows, conflict pad)
__global__ __launch_bounds__(256) void gat_scores(
    const float* __restrict__ ejB, const float* __restrict__ ajF,
    const float* __restrict__ ei, const float* __restrict__ aiF,
    const float* __restrict__ attn_w1, const float* __restrict__ attn_w2,
    const float* __restrict__ attn_b2, const int* __restrict__ adj,
    float* __restrict__ e_out)
{
    const int tid  = threadIdx.x;
    const int lane = tid & 63;
    const int wid  = tid >> 6;
    const int nloc = lane & 15;
    const int quad = lane >> 4;
    const int i0   = (blockIdx.x >> 4) * IG;
    const int j16  = (blockIdx.x & 15) * 64 + wid * 16;
    const float* __restrict__ Ae = attn_w1 + 2 * D * D;

    __shared__ __align__(16) float sv[IG][D];     // ei rows
    __shared__ __align__(16) float av[IG][D];     // aiF rows
    __shared__ __align__(16) short AeT[D * AEK];  // 0.4*Ae^T bf16, ~9 KB

    {
        float* svf = &sv[0][0];
        float* avf = &av[0][0];
        #pragma unroll
        for (int c = 0; c < IG * D / 256; ++c) {
            svf[c * 256 + tid] = ei[(size_t)i0 * D + c * 256 + tid];
            avf[c * 256 + tid] = aiF[(size_t)i0 * D + c * 256 + tid];
        }
        // stage 0.4*Ae -> AeT[o][k] (bf16, transposed). 4 passes x float4.
        #pragma unroll
        for (int p = 0; p < 4; ++p) {
            const int base = p * 1024 + tid * 4;      // linear into Ae
            const int k = base >> 6;                  // row of Ae
            const int o = base & 63;                  // col of Ae (4 consec)
            const f32x4 v = *(const f32x4*)(Ae + base) * 0.4f;
            AeT[(o + 0) * AEK + k] = f2bf(v.x);
            AeT[(o + 1) * AEK + k] = f2bf(v.y);
            AeT[(o + 2) * AEK + k] = f2bf(v.z);
            AeT[(o + 3) * AEK + k] = f2bf(v.w);
        }
    }
    __syncthreads();

    // A fragments from LDS: Bf[kt][ot] = AeT[ot*16+nloc][kt*32+quad*8 ..+7]
    bf16x8 Bf[2][4];
    #pragma unroll
    for (int kt = 0; kt < 2; ++kt)
        #pragma unroll
        for (int ot = 0; ot < 4; ++ot)
            Bf[kt][ot] = *(const bf16x8*)(&AeT[(ot * 16 + nloc) * AEK + kt * 32 + quad * 8]);

    // w2 per lane: o = ot*16 + quad*4 + r  (f32x4 over r)
    f32x4 w2l[4];
    #pragma unroll
    for (int ot = 0; ot < 4; ++ot)
        w2l[ot] = *(const f32x4*)(attn_w2 + ot * 16 + quad * 4);
    const float b2 = attn_b2[0];
    const int k0 = quad * 8;

    // j-side loads: once per wave, reused over IG i's
    const float* __restrict__ ejr = ejB + (size_t)(j16 + nloc) * D;
    const f32x4 ev0 = *(const f32x4*)(ejr + k0);
    const f32x4 ev1 = *(const f32x4*)(ejr + k0 + 4);
    const f32x4 ev2 = *(const f32x4*)(ejr + 32 + k0);
    const f32x4 ev3 = *(const f32x4*)(ejr + 32 + k0 + 4);
    // C-init tile: ajF[j=j16+nloc][o=ot*16+quad*4 .. +3]
    const float* __restrict__ ajr = ajF + (size_t)(j16 + nloc) * D;
    f32x4 ajv[4];
    #pragma unroll
    for (int ot = 0; ot < 4; ++ot)
        ajv[ot] = *(const f32x4*)(ajr + ot * 16 + quad * 4);

    // adj prefetch (value used by lanes<16; all lanes load their nloc word)
    int adjv[IG];
    #pragma unroll
    for (int ii = 0; ii < IG; ++ii)
        adjv[ii] = adj[(size_t)(i0 + ii) * N + j16 + nloc];

    // ---- loop 1: independent per-ii chains, no cross-lane ops ------------
    float epart[IG];
    #pragma unroll
    for (int ii = 0; ii < IG; ++ii) {
        const f32x4 s0 = *(const f32x4*)(&sv[ii][k0]);
        const f32x4 s1 = *(const f32x4*)(&sv[ii][k0 + 4]);
        const f32x4 s2 = *(const f32x4*)(&sv[ii][32 + k0]);
        const f32x4 s3 = *(const f32x4*)(&sv[ii][32 + k0 + 4]);

        BF8 af0, af1;
        f32x4 t;
        t = ev0 + s0; af0.u[0] = abs_cvt_pair(t.x, t.y); af0.u[1] = abs_cvt_pair(t.z, t.w);
        t = ev1 + s1; af0.u[2] = abs_cvt_pair(t.x, t.y); af0.u[3] = abs_cvt_pair(t.z, t.w);
        t = ev2 + s2; af1.u[0] = abs_cvt_pair(t.x, t.y); af1.u[1] = abs_cvt_pair(t.z, t.w);
        t = ev3 + s3; af1.u[2] = abs_cvt_pair(t.x, t.y); af1.u[3] = abs_cvt_pair(t.z, t.w);

        f32x4 acc[4];
        #pragma unroll
        for (int ot = 0; ot < 4; ++ot) {
            acc[ot] = __builtin_amdgcn_mfma_f32_16x16x32_bf16(Bf[0][ot], af0.v, ajv[ot], 0, 0, 0);
            acc[ot] = __builtin_amdgcn_mfma_f32_16x16x32_bf16(Bf[1][ot], af1.v, acc[ot], 0, 0, 0);
        }

        f32x4 e4 = {0.f, 0.f, 0.f, 0.f};
        #pragma unroll
        for (int ot = 0; ot < 4; ++ot) {
            const f32x4 avl = *(const f32x4*)(&av[ii][ot * 16 + quad * 4]);
            e4 += leaky4(acc[ot] + avl) * w2l[ot];
        }
        epart[ii] = (e4.x + e4.y) + (e4.z + e4.w);
    }

    // ---- loop 2: batched cross-lane reduce (pipelined DS ops) ------------
    #pragma unroll
    for (int ii = 0; ii < IG; ++ii)
        epart[ii] += __shfl_xor(epart[ii], 16, 64);
    #pragma unroll
    for (int ii = 0; ii < IG; ++ii)
        epart[ii] += __shfl_xor(epart[ii], 32, 64);

    // ---- loop 3: masked stores -------------------------------------------
    if (lane < 16) {
        #pragma unroll
        for (int ii = 0; ii < IG; ++ii) {
            const size_t idx = (size_t)(i0 + ii) * N + j16 + lane;
            e_out[idx] = adjv[ii] ? (epart[ii] + b2) : MASK_VAL;
        }
    }
}

// ---------------------------------------------------------------------------
// Kernel 3: softmax + aggregation + layernorm. Block = 2 rows x 256 threads.
// e is pre-masked. Each Wh load feeds both rows.
// ---------------------------------------------------------------------------
__global__ __launch_bounds__(256) void gat_softagg(
    const float* __restrict__ e_in, const float* __restrict__ Wh,
    const float* __restrict__ h, const float* __restrict__ ln_g,
    const float* __restrict__ ln_b, float* __restrict__ out)
{
    const int tid  = threadIdx.x;
    const int lane = tid & 63;
    const int wid  = tid >> 6;
    const int i0   = blockIdx.x * 2;
    const int r    = wid >> 1;
    const int half = wid & 1;

    __shared__ float p[2][N];       // 8 KB
    __shared__ float wred[4][2];    // per-wave max, sum
    __shared__ float red[4][2][D];  // 2 KB

    {
        const float* __restrict__ erow = e_in + (size_t)(i0 + r) * N;
        float m = -INFINITY;
        #pragma unroll
        for (int c = 0; c < 8; ++c) {
            int j = half * 512 + c * 64 + lane;
            float v = erow[j];
            p[r][j] = v;
            m = fmaxf(m, v);
        }
        #pragma unroll
        for (int off = 32; off >= 1; off >>= 1) m = fmaxf(m, __shfl_xor(m, off, 64));
        if (lane == 0) wred[wid][0] = m;
    }
    __syncthreads();
    {
        float m = fmaxf(wred[r * 2][0], wred[r * 2 + 1][0]);
        float s = 0.f;
        #pragma unroll
        for (int c = 0; c < 8; ++c) {
            int j = half * 512 + c * 64 + lane;
            float pv = __expf(p[r][j] - m);
            p[r][j] = pv;
            s += pv;
        }
        #pragma unroll
        for (int off = 32; off >= 1; off >>= 1) s += __shfl_xor(s, off, 64);
        if (lane == 0) wred[wid][1] = s;
    }
    __syncthreads();

    {
        const int k = lane, g = wid;
        float hp0 = 0.f, hp1 = 0.f;
        #pragma unroll 8
        for (int jj = 0; jj < 256; ++jj) {
            const int j = g * 256 + jj;
            const float whv = Wh[(size_t)j * D + k];
            hp0 = fmaf(p[0][j], whv, hp0);
            hp1 = fmaf(p[1][j], whv, hp1);
        }
        red[g][0][k] = hp0;
        red[g][1][k] = hp1;
    }
    __syncthreads();

    if (wid < 2) {
        const int rr = wid;
        const float inv_s = 1.f / (wred[rr * 2][1] + wred[rr * 2 + 1][1]);
        float v = (red[0][rr][lane] + red[1][rr][lane] +
                   red[2][rr][lane] + red[3][rr][lane]) * inv_s
                  + h[(size_t)(i0 + rr) * D + lane];
        float mu = v;
        #pragma unroll
        for (int off = 32; off >= 1; off >>= 1) mu += __shfl_xor(mu, off, 64);
        mu *= (1.f / D);
        float d = v - mu;
        float var = d * d;
        #pragma unroll
        for (int off = 32; off >= 1; off >>= 1) var += __shfl_xor(var, off, 64);
        var *= (1.f / D);
        out[(size_t)(i0 + rr) * D + lane] = d * rsqrtf(var + LN_EPS) * ln_g[lane] + ln_b[lane];
    }
}

// ---------------------------------------------------------------------------
extern "C" void kernel_launch(void* const* d_in, const int* in_sizes, int n_in,
                              void* d_out, int out_size, void* d_ws, size_t ws_size,
                              hipStream_t stream) {
    const float* h       = (const float*)d_in[0];
    const int*   adj     = (const int*)  d_in[1];
    const float* W       = (const float*)d_in[2];
    const float* attn_w1 = (const float*)d_in[3];
    const float* attn_b1 = (const float*)d_in[4];
    const float* attn_w2 = (const float*)d_in[5];
    const float* attn_b2 = (const float*)d_in[6];
    const float* edge_w  = (const float*)d_in[7];
    const float* edge_b  = (const float*)d_in[8];
    const float* ln_g    = (const float*)d_in[9];
    const float* ln_b    = (const float*)d_in[10];
    float* out = (float*)d_out;

    float* ws   = (float*)d_ws;
    float* Wh   = ws + 0 * (N * D);
    float* ejB  = ws + 1 * (N * D);
    float* ei_w = ws + 2 * (N * D);
    float* ajF  = ws + 3 * (N * D);
    float* aiF  = ws + 4 * (N * D);
    float* e    = ws + 5 * (N * D);   // N*N floats = 4 MB

    gat_precompute<<<N / 4, 256, 0, stream>>>(h, W, attn_w1, attn_b1, edge_w, edge_b,
                                              Wh, ejB, ei_w, ajF, aiF);
    gat_scores<<<(N / IG) * 16, 256, 0, stream>>>(ejB, ajF, ei_w, aiF,
                                                  attn_w1, attn_w2, attn_b2, adj, e);
    gat_softagg<<<N / 2, 256, 0, stream>>>(e, Wh, h, ln_g, ln_b, out);
}

// Round 15
// 119.828 us; speedup vs baseline: 1.0681x; 1.0681x over previous
//
#include <hip/hip_runtime.h>
#include <hip/hip_bf16.h>
#include <math.h>

#define N 1024
#define D 64
#define ALPHA 0.2f
#define LN_EPS 1e-5f
#define MASK_VAL -1000000000.0f

typedef __attribute__((ext_vector_type(8))) short bf16x8;
typedef __attribute__((ext_vector_type(4))) float f32x4;

__device__ __forceinline__ float leaky(float x) { return fmaxf(x, ALPHA * x); }

__device__ __forceinline__ unsigned f2bf_u(float f) {
    unsigned u = __builtin_bit_cast(unsigned, f);
    u += 0x7fffu + ((u >> 16) & 1u);
    return u >> 16;
}
__device__ __forceinline__ short f2bf(float f) { return (short)f2bf_u(f); }

// |x|,|y| -> packed bf16 dword via hw v_cvt_pk_bf16_f32 (abs folds into
// VOP3 src modifiers).
__device__ __forceinline__ unsigned abs_cvt_pair(float x, float y) {
    __hip_bfloat162 b = __float22bfloat162_rn(make_float2(fabsf(x), fabsf(y)));
    unsigned u;
    __builtin_memcpy(&u, &b, 4);
    return u;
}

__device__ __forceinline__ f32x4 leaky4(f32x4 v) {
    return __builtin_elementwise_max(v, v * ALPHA);
}

union BF8 { bf16x8 v; unsigned u[4]; };

// ---------------------------------------------------------------------------
// Kernel 1: projections + leaky factoring folds. 4 rows per block.
//   leaky(X) = 0.6X + 0.4|X|, X = ei + ejB (ejB includes edge_b) =>
//   ajF = Wh@A_j + 0.6*(ejB@Ae)       (row-major [j][o])
//   aiF = Wh@A_i + b1 + 0.6*(ei@Ae)
// ---------------------------------------------------------------------------
__global__ __launch_bounds__(256) void gat_precompute(
    const float* __restrict__ h, const float* __restrict__ W,
    const float* __restrict__ attn_w1, const float* __restrict__ attn_b1,
    const float* __restrict__ edge_w, const float* __restrict__ edge_b,
    float* __restrict__ Wh, float* __restrict__ ejB, float* __restrict__ ei_o,
    float* __restrict__ ajF, float* __restrict__ aiF)
{
    const int tid = threadIdx.x;
    const int r = tid >> 6;
    const int k = tid & 63;
    const int i = blockIdx.x * 4 + r;
    const float* __restrict__ Ae = attn_w1 + 2 * D * D;
    __shared__ float hrow[4][D], whrow[4][D], eirow[4][D], ejrow[4][D];

    hrow[r][k] = h[(size_t)i * D + k];
    __syncthreads();

    float wh = 0.f, vei = 0.f, vej = 0.f;
    #pragma unroll 8
    for (int m = 0; m < D; ++m) {
        float hm = hrow[r][m];
        wh  = fmaf(hm, W[m * D + k], wh);
        vei = fmaf(hm, edge_w[m * D + k], vei);
        vej = fmaf(hm, edge_w[(m + D) * D + k], vej);
    }
    vej += edge_b[k];
    Wh[(size_t)i * D + k]   = wh;
    ei_o[(size_t)i * D + k] = vei;
    ejB[(size_t)i * D + k]  = vej;
    whrow[r][k] = wh; eirow[r][k] = vei; ejrow[r][k] = vej;
    __syncthreads();

    float vai = 0.f, vaj = 0.f, vea = 0.f, veb = 0.f;
    #pragma unroll 8
    for (int m = 0; m < D; ++m) {
        float wm = whrow[r][m];
        float aem = Ae[m * D + k];
        vai = fmaf(wm, attn_w1[m * D + k], vai);
        vaj = fmaf(wm, attn_w1[(m + D) * D + k], vaj);
        vea = fmaf(ejrow[r][m], aem, vea);
        veb = fmaf(eirow[r][m], aem, veb);
    }
    ajF[(size_t)i * D + k] = vaj + 0.6f * vea;
    aiF[(size_t)i * D + k] = vai + attn_b1[k] + 0.6f * veb;
}

// ---------------------------------------------------------------------------
// Kernel 2: scores. Block = 8 i's x 64 j's; grid 2048 x 4 waves.
// (R15: revert to the measured-optimal R13 config — IG=8. IG=4 regressed:
// at full residency more blocks only double the per-block fixed staging.)
// 0.4*Ae staged via LDS transposed bf16 (AeT[o][k], stride 72).
// ---------------------------------------------------------------------------
#define IG 8
#define AEK 72   // AeT row stride in shorts (16B-aligned rows, conflict pad)
__global__ __launch_bounds__(256) void gat_scores(
    const float* __restrict__ ejB, const float* __restrict__ ajF,
    const float* __restrict__ ei, const float* __restrict__ aiF,
    const float* __restrict__ attn_w1, const float* __restrict__ attn_w2,
    const float* __restrict__ attn_b2, const int* __restrict__ adj,
    float* __restrict__ e_out)
{
    const int tid  = threadIdx.x;
    const int lane = tid & 63;
    const int wid  = tid >> 6;
    const int nloc = lane & 15;
    const int quad = lane >> 4;
    const int i0   = (blockIdx.x >> 4) * IG;
    const int j16  = (blockIdx.x & 15) * 64 + wid * 16;
    const float* __restrict__ Ae = attn_w1 + 2 * D * D;

    __shared__ __align__(16) float sv[IG][D];     // ei rows
    __shared__ __align__(16) float av[IG][D];     // aiF rows
    __shared__ __align__(16) short AeT[D * AEK];  // 0.4*Ae^T bf16, ~9 KB

    {
        float* svf = &sv[0][0];
        float* avf = &av[0][0];
        #pragma unroll
        for (int c = 0; c < IG * D / 256; ++c) {
            svf[c * 256 + tid] = ei[(size_t)i0 * D + c * 256 + tid];
            avf[c * 256 + tid] = aiF[(size_t)i0 * D + c * 256 + tid];
        }
        // stage 0.4*Ae -> AeT[o][k] (bf16, transposed). 4 passes x float4.
        #pragma unroll
        for (int p = 0; p < 4; ++p) {
            const int base = p * 1024 + tid * 4;      // linear into Ae
            const int k = base >> 6;                  // row of Ae
            const int o = base & 63;                  // col of Ae (4 consec)
            const f32x4 v = *(const f32x4*)(Ae + base) * 0.4f;
            AeT[(o + 0) * AEK + k] = f2bf(v.x);
            AeT[(o + 1) * AEK + k] = f2bf(v.y);
            AeT[(o + 2) * AEK + k] = f2bf(v.z);
            AeT[(o + 3) * AEK + k] = f2bf(v.w);
        }
    }
    __syncthreads();

    // A fragments from LDS: Bf[kt][ot] = AeT[ot*16+nloc][kt*32+quad*8 ..+7]
    bf16x8 Bf[2][4];
    #pragma unroll
    for (int kt = 0; kt < 2; ++kt)
        #pragma unroll
        for (int ot = 0; ot < 4; ++ot)
            Bf[kt][ot] = *(const bf16x8*)(&AeT[(ot * 16 + nloc) * AEK + kt * 32 + quad * 8]);

    // w2 per lane: o = ot*16 + quad*4 + r  (f32x4 over r)
    f32x4 w2l[4];
    #pragma unroll
    for (int ot = 0; ot < 4; ++ot)
        w2l[ot] = *(const f32x4*)(attn_w2 + ot * 16 + quad * 4);
    const float b2 = attn_b2[0];
    const int k0 = quad * 8;

    // j-side loads: once per wave, reused over IG i's
    const float* __restrict__ ejr = ejB + (size_t)(j16 + nloc) * D;
    const f32x4 ev0 = *(const f32x4*)(ejr + k0);
    const f32x4 ev1 = *(const f32x4*)(ejr + k0 + 4);
    const f32x4 ev2 = *(const f32x4*)(ejr + 32 + k0);
    const f32x4 ev3 = *(const f32x4*)(ejr + 32 + k0 + 4);
    // C-init tile: ajF[j=j16+nloc][o=ot*16+quad*4 .. +3]
    const float* __restrict__ ajr = ajF + (size_t)(j16 + nloc) * D;
    f32x4 ajv[4];
    #pragma unroll
    for (int ot = 0; ot < 4; ++ot)
        ajv[ot] = *(const f32x4*)(ajr + ot * 16 + quad * 4);

    // adj prefetch (value used by lanes<16; all lanes load their nloc word)
    int adjv[IG];
    #pragma unroll
    for (int ii = 0; ii < IG; ++ii)
        adjv[ii] = adj[(size_t)(i0 + ii) * N + j16 + nloc];

    // ---- loop 1: independent per-ii chains, no cross-lane ops ------------
    float epart[IG];
    #pragma unroll
    for (int ii = 0; ii < IG; ++ii) {
        const f32x4 s0 = *(const f32x4*)(&sv[ii][k0]);
        const f32x4 s1 = *(const f32x4*)(&sv[ii][k0 + 4]);
        const f32x4 s2 = *(const f32x4*)(&sv[ii][32 + k0]);
        const f32x4 s3 = *(const f32x4*)(&sv[ii][32 + k0 + 4]);

        BF8 af0, af1;
        f32x4 t;
        t = ev0 + s0; af0.u[0] = abs_cvt_pair(t.x, t.y); af0.u[1] = abs_cvt_pair(t.z, t.w);
        t = ev1 + s1; af0.u[2] = abs_cvt_pair(t.x, t.y); af0.u[3] = abs_cvt_pair(t.z, t.w);
        t = ev2 + s2; af1.u[0] = abs_cvt_pair(t.x, t.y); af1.u[1] = abs_cvt_pair(t.z, t.w);
        t = ev3 + s3; af1.u[2] = abs_cvt_pair(t.x, t.y); af1.u[3] = abs_cvt_pair(t.z, t.w);

        f32x4 acc[4];
        #pragma unroll
        for (int ot = 0; ot < 4; ++ot) {
            acc[ot] = __builtin_amdgcn_mfma_f32_16x16x32_bf16(Bf[0][ot], af0.v, ajv[ot], 0, 0, 0);
            acc[ot] = __builtin_amdgcn_mfma_f32_16x16x32_bf16(Bf[1][ot], af1.v, acc[ot], 0, 0, 0);
        }

        f32x4 e4 = {0.f, 0.f, 0.f, 0.f};
        #pragma unroll
        for (int ot = 0; ot < 4; ++ot) {
            const f32x4 avl = *(const f32x4*)(&av[ii][ot * 16 + quad * 4]);
            e4 += leaky4(acc[ot] + avl) * w2l[ot];
        }
        epart[ii] = (e4.x + e4.y) + (e4.z + e4.w);
    }

    // ---- loop 2: batched cross-lane reduce (pipelined DS ops) ------------
    #pragma unroll
    for (int ii = 0; ii < IG; ++ii)
        epart[ii] += __shfl_xor(epart[ii], 16, 64);
    #pragma unroll
    for (int ii = 0; ii < IG; ++ii)
        epart[ii] += __shfl_xor(epart[ii], 32, 64);

    // ---- loop 3: masked stores -------------------------------------------
    if (lane < 16) {
        #pragma unroll
        for (int ii = 0; ii < IG; ++ii) {
            const size_t idx = (size_t)(i0 + ii) * N + j16 + lane;
            e_out[idx] = adjv[ii] ? (epart[ii] + b2) : MASK_VAL;
        }
    }
}

// ---------------------------------------------------------------------------
// Kernel 3: softmax + aggregation + layernorm. Block = 2 rows x 256 threads.
// e is pre-masked. Each Wh load feeds both rows.
// ---------------------------------------------------------------------------
__global__ __launch_bounds__(256) void gat_softagg(
    const float* __restrict__ e_in, const float* __restrict__ Wh,
    const float* __restrict__ h, const float* __restrict__ ln_g,
    const float* __restrict__ ln_b, float* __restrict__ out)
{
    const int tid  = threadIdx.x;
    const int lane = tid & 63;
    const int wid  = tid >> 6;
    const int i0   = blockIdx.x * 2;
    const int r    = wid >> 1;
    const int half = wid & 1;

    __shared__ float p[2][N];       // 8 KB
    __shared__ float wred[4][2];    // per-wave max, sum
    __shared__ float red[4][2][D];  // 2 KB

    {
        const float* __restrict__ erow = e_in + (size_t)(i0 + r) * N;
        float m = -INFINITY;
        #pragma unroll
        for (int c = 0; c < 8; ++c) {
            int j = half * 512 + c * 64 + lane;
            float v = erow[j];
            p[r][j] = v;
            m = fmaxf(m, v);
        }
        #pragma unroll
        for (int off = 32; off >= 1; off >>= 1) m = fmaxf(m, __shfl_xor(m, off, 64));
        if (lane == 0) wred[wid][0] = m;
    }
    __syncthreads();
    {
        float m = fmaxf(wred[r * 2][0], wred[r * 2 + 1][0]);
        float s = 0.f;
        #pragma unroll
        for (int c = 0; c < 8; ++c) {
            int j = half * 512 + c * 64 + lane;
            float pv = __expf(p[r][j] - m);
            p[r][j] = pv;
            s += pv;
        }
        #pragma unroll
        for (int off = 32; off >= 1; off >>= 1) s += __shfl_xor(s, off, 64);
        if (lane == 0) wred[wid][1] = s;
    }
    __syncthreads();

    {
        const int k = lane, g = wid;
        float hp0 = 0.f, hp1 = 0.f;
        #pragma unroll 8
        for (int jj = 0; jj < 256; ++jj) {
            const int j = g * 256 + jj;
            const float whv = Wh[(size_t)j * D + k];
            hp0 = fmaf(p[0][j], whv, hp0);
            hp1 = fmaf(p[1][j], whv, hp1);
        }
        red[g][0][k] = hp0;
        red[g][1][k] = hp1;
    }
    __syncthreads();

    if (wid < 2) {
        const int rr = wid;
        const float inv_s = 1.f / (wred[rr * 2][1] + wred[rr * 2 + 1][1]);
        float v = (red[0][rr][lane] + red[1][rr][lane] +
                   red[2][rr][lane] + red[3][rr][lane]) * inv_s
                  + h[(size_t)(i0 + rr) * D + lane];
        float mu = v;
        #pragma unroll
        for (int off = 32; off >= 1; off >>= 1) mu += __shfl_xor(mu, off, 64);
        mu *= (1.f / D);
        float d = v - mu;
        float var = d * d;
        #pragma unroll
        for (int off = 32; off >= 1; off >>= 1) var += __shfl_xor(var, off, 64);
        var *= (1.f / D);
        out[(size_t)(i0 + rr) * D + lane] = d * rsqrtf(var + LN_EPS) * ln_g[lane] + ln_b[lane];
    }
}

// ---------------------------------------------------------------------------
extern "C" void kernel_launch(void* const* d_in, const int* in_sizes, int n_in,
                              void* d_out, int out_size, void* d_ws, size_t ws_size,
                              hipStream_t stream) {
    const float* h       = (const float*)d_in[0];
    const int*   adj     = (const int*)  d_in[1];
    const float* W       = (const float*)d_in[2];
    const float* attn_w1 = (const float*)d_in[3];
    const float* attn_b1 = (const float*)d_in[4];
    const float* attn_w2 = (const float*)d_in[5];
    const float* attn_b2 = (const float*)d_in[6];
    const float* edge_w  = (const float*)d_in[7];
    const float* edge_b  = (const float*)d_in[8];
    const float* ln_g    = (const float*)d_in[9];
    const float* ln_b    = (const float*)d_in[10];
    float* out = (float*)d_out;

    float* ws   = (float*)d_ws;
    float* Wh   = ws + 0 * (N * D);
    float* ejB  = ws + 1 * (N * D);
    float* ei_w = ws + 2 * (N * D);
    float* ajF  = ws + 3 * (N * D);
    float* aiF  = ws + 4 * (N * D);
    float* e    = ws + 5 * (N * D);   // N*N floats = 4 MB

    gat_precompute<<<N / 4, 256, 0, stream>>>(h, W, attn_w1, attn_b1, edge_w, edge_b,
                                              Wh, ejB, ei_w, ajF, aiF);
    gat_scores<<<(N / IG) * 16, 256, 0, stream>>>(ejB, ajF, ei_w, aiF,
                                                  attn_w1, attn_w2, attn_b2, adj, e);
    gat_softagg<<<N / 2, 256, 0, stream>>>(e, Wh, h, ln_g, ln_b, out);
}